// Round 7
// baseline (602.942 us; speedup 1.0000x reference)
//
#include <hip/hip_runtime.h>
#include <hip/hip_bf16.h>
#include <hip/hip_fp16.h>

// B=8, T(N)=256, F=256, K=2, H=128, gates=512, 2H=256.
//
// Exact math simplifications (data-independent):
//  - LayerNorm over size-1 dim => TG = 1/256 exactly.
//  - A_hat rowsum == 2.0 exactly => cheb out = x@(W0+0.5*W1) + (colsum/512)@W1
//    + cheb_b -> LayerNorm(256).
//  - BiLSTM: 16 independent recurrences per layer (2 dir x 8 batch).
//
// R6->R7: k_lstm rebuilt. Root cause of the 1630-cyc step: 128 broadcast
// ds_read_b128/step (h into every lane) + 2 __syncthreads (each with
// compiler-forced vmcnt(0) drain killing prefetch). Now: K-split GEMV
// (quad lanes share column J, split K 4-way; h reads 16-lane-shared ->
// 32 LDS instrs/step), quad shfl_xor reduce, interleaved gate permutation
// (slots J*4+g) so each quad owns all 4 gates of its column -> no reducer
// phase; ONE raw barrier/step (s_waitcnt lgkmcnt(0); s_barrier - no vmcnt
// drain) + double-buffered h; gin register prefetch depth 2 now effective.
// Also: ballot-based dtype detect per block (k_detect dropped), prep
// kernels fused (13 -> 9 launches).

typedef unsigned short u16;
typedef unsigned int u32;
typedef _Float16 h2_t __attribute__((ext_vector_type(2)));

__device__ __forceinline__ float bf2f(u16 v) { return __uint_as_float(((u32)v) << 16); }
__device__ __forceinline__ u16 f2bf(float f) {
    u32 u = __float_as_uint(f);
    u32 r = (u + 0x7fffu + ((u >> 16) & 1u)) >> 16;
    return (u16)r;
}
__device__ __forceinline__ float sigm(float x) { return 1.0f / (1.0f + __expf(-x)); }
__device__ __forceinline__ float tanh_f(float x) { return 1.0f - 2.0f / (__expf(2.0f * x) + 1.0f); }
__device__ __forceinline__ float ldin(const void* p, long long i, int f32) {
    return f32 ? ((const float*)p)[i] : bf2f(((const u16*)p)[i]);
}
__device__ __forceinline__ void store_out(void* out, long long idx, float v, int f32) {
    if (f32) ((float*)out)[idx] = v;
    else ((u16*)out)[idx] = f2bf(v);
}
__device__ __forceinline__ h2_t as_h2(u32 w) { return __builtin_bit_cast(h2_t, w); }

// per-wave dtype detect: low u16 of fp32 words has random high mantissa bits;
// real bf16 data never has |x| >= 2^17. fp32 => E[popc] ~ 28/64, bf16 => 0.
__device__ __forceinline__ int detect_f32(const u32* __restrict__ xraw) {
    u32 w = xraw[threadIdx.x & 255];
    int e = (w >> 7) & 0xFF;
    unsigned long long m = __ballot(e >= 0x90);
    return __popcll(m) > 8;
}

// workgroup barrier draining ONLY lgkmcnt (LDS) - no vmcnt(0) drain, so
// in-flight global loads/stores survive the barrier.
__device__ __forceinline__ void bar_lds() {
    asm volatile("s_waitcnt lgkmcnt(0)\n\ts_barrier" ::: "memory");
}

// ---- ws layout (BYTE offsets), total ~7.35 MB ------------------------------
#define WB_S    64        // fp32 [8192]   colsum partials (32 x 256)
#define WB_TBP  41024     // fp32 [16384]  tb partials (64 x 256)
#define WB_WC   106560    // fp32 [65536]
#define WB_WT   368704    // fp16 [524288] WihT (j-dim PERMUTED: slot J*4+g)
#define WB_M1   1417280   // fp16 [524288] hbuf0 (cheb out), later lnout
#define WB_M2   2465856   // fp16 [524288] hcat0, later hcat1
#define WB_GIN  3514432   // fp16 [2097152] gate inputs (permuted j), one layer

// ---- fused prep: wc | fill_tg | colsum | wih_t(permuted) -------------------
__global__ __launch_bounds__(256) void k_prep(const u32* __restrict__ xraw,
                                              const void* __restrict__ chw,
                                              const void* __restrict__ wih,
                                              void* out, float* __restrict__ Wc,
                                              float* __restrict__ Sp,
                                              __half* __restrict__ WT) {
    __shared__ __half tile[64][65];
    int f32 = detect_f32(xraw);
    int bid = blockIdx.x;
    int tid = threadIdx.x;
    if (bid < 256) { // Wc = W0 + 0.5*W1
        int i = bid * 256 + tid;
        Wc[i] = ldin(chw, i, f32) + 0.5f * ldin(chw, 65536 + i, f32);
    } else if (bid < 768) { // TG fill = 1/256
        long long i = (long long)(bid - 256) * 256 + tid;
        if (f32) {
            float4 v{0.00390625f, 0.00390625f, 0.00390625f, 0.00390625f};
            ((float4*)((float*)out + 2048))[i] = v;
        } else {
            uint2 v{0x3B803B80u, 0x3B803B80u};
            ((uint2*)((u16*)out + 2048))[i] = v;
        }
    } else if (bid < 800) { // colsum partials over 64 rows
        int blk = bid - 768;
        int b = blk >> 2, ch = blk & 3;
        float s = 0.f;
        int n0 = ch * 64;
        for (int n = n0; n < n0 + 64; n++)
            s += ldin(xraw, ((long long)(b * 256 + n)) * 256 + tid, f32);
        Sp[blk * 256 + tid] = s;
    } else { // wih transpose -> WT[ld][f][perm(j)], perm(j) = (j&127)*4 + (j>>7)
        int q = bid - 800;
        int ld = q >> 5;
        int jt = ((q >> 2) & 7) * 64;
        int ft = (q & 3) * 64;
        int lane = tid & 63;
        int wv = tid >> 6;
#pragma unroll
        for (int r = wv; r < 64; r += 4)
            tile[r][lane] = __float2half(ldin(wih, ((long long)(ld * 512 + jt + r)) * 256 + ft + lane, f32));
        __syncthreads();
#pragma unroll
        for (int r = wv; r < 64; r += 4) {
            int j = jt + lane;
            int pj = ((j & 127) << 2) | (j >> 7);
            WT[((long long)ld * 256 + ft + r) * 512 + pj] = tile[lane][r];
        }
    }
}

// ---- tb partials: tbp[b*8+fc][o] over f in [fc*32, fc*32+32) ---------------
__global__ void k_tb1(const float* __restrict__ Sp, const void* __restrict__ chw,
                      float* __restrict__ tbp, const u32* __restrict__ xraw) {
    int f32 = detect_f32(xraw);
    int blk = blockIdx.x;
    int b = blk >> 3, fc = blk & 7;
    int o = threadIdx.x;
    float acc = 0.f;
    const float cs = 1.0f / 512.0f;
    int f0 = fc * 32;
    for (int f = f0; f < f0 + 32; f++) {
        float s = Sp[(b * 4 + 0) * 256 + f] + Sp[(b * 4 + 1) * 256 + f] +
                  Sp[(b * 4 + 2) * 256 + f] + Sp[(b * 4 + 3) * 256 + f];
        acc = fmaf(s * cs, ldin(chw, 65536 + f * 256 + o, f32), acc);
    }
    tbp[blk * 256 + o] = acc;
}

// ---- cheb row GEMM + tb merge + LayerNorm(256) -> M1 fp16 ------------------
__global__ void k_cheb_ln(const void* __restrict__ x, const float* __restrict__ Wc,
                          const float* __restrict__ tbp, const void* __restrict__ chb,
                          const void* __restrict__ g, const void* __restrict__ bb,
                          __half* __restrict__ out, const u32* __restrict__ xraw) {
    __shared__ float xr[256];
    __shared__ float red1[4], red2[4];
    int f32 = detect_f32(xraw);
    int row = blockIdx.x;
    int b = row >> 8;
    int o = threadIdx.x;
    xr[o] = ldin(x, row * 256 + o, f32);
    __syncthreads();
    float acc = ldin(chb, o, f32);
#pragma unroll
    for (int fc = 0; fc < 8; fc++) acc += tbp[(b * 8 + fc) * 256 + o];
    const float4* x4 = (const float4*)xr;
#pragma unroll 8
    for (int q = 0; q < 64; q++) {
        float4 xv = x4[q];
        int f = q * 4;
        acc = fmaf(xv.x, Wc[f * 256 + o], acc);
        acc = fmaf(xv.y, Wc[(f + 1) * 256 + o], acc);
        acc = fmaf(xv.z, Wc[(f + 2) * 256 + o], acc);
        acc = fmaf(xv.w, Wc[(f + 3) * 256 + o], acc);
    }
    float s1 = acc, s2 = acc * acc;
    for (int off = 32; off >= 1; off >>= 1) {
        s1 += __shfl_xor(s1, off, 64);
        s2 += __shfl_xor(s2, off, 64);
    }
    if ((o & 63) == 0) { red1[o >> 6] = s1; red2[o >> 6] = s2; }
    __syncthreads();
    float S1 = red1[0] + red1[1] + red1[2] + red1[3];
    float S2 = red2[0] + red2[1] + red2[2] + red2[3];
    float m = S1 * (1.0f / 256.0f);
    float var = S2 * (1.0f / 256.0f) - m * m;
    float rstd = rsqrtf(var + 1e-5f);
    out[row * 256 + o] = __float2half((acc - m) * rstd * ldin(g, o, f32) + ldin(bb, o, f32));
}

// ---- gin[d][b][t][jr] = in[b][t] @ WT(perm) + bias(orig) -------------------
__global__ __launch_bounds__(512) void k_gin(const __half* __restrict__ in,
                                             const __half* __restrict__ WT,
                                             const void* __restrict__ bih,
                                             const void* __restrict__ bhh,
                                             __half* __restrict__ gin, int l,
                                             const u32* __restrict__ xraw) {
    __shared__ float inl[16 * 256];
    int f32 = detect_f32(xraw);
    int d = blockIdx.x >> 7;
    int rb = (blockIdx.x & 127) * 16;
    int j = threadIdx.x; // PERMUTED slot: orig row = (j&3)*128 + (j>>2)
    const __half2* src = (const __half2*)(in + (size_t)rb * 256);
    float2* dst = (float2*)inl;
#pragma unroll
    for (int q = 0; q < 4; q++)
        dst[j + q * 512] = __half22float2(src[j + q * 512]);
    __syncthreads();
    int ld = l * 2 + d;
    int oj = ((j & 3) << 7) | (j >> 2);
    float bias = ldin(bih, ld * 512 + oj, f32) + ldin(bhh, ld * 512 + oj, f32);
    float acc[16];
#pragma unroll
    for (int r = 0; r < 16; r++) acc[r] = bias;
    const __half* W = WT + (size_t)ld * 131072;
    for (int fq = 0; fq < 64; fq++) {
        int f = fq * 4;
        float w0 = __half2float(W[(f + 0) * 512 + j]);
        float w1 = __half2float(W[(f + 1) * 512 + j]);
        float w2 = __half2float(W[(f + 2) * 512 + j]);
        float w3 = __half2float(W[(f + 3) * 512 + j]);
#pragma unroll
        for (int r = 0; r < 16; r++) {
            const float4 iv = ((const float4*)(inl + r * 256))[fq];
            acc[r] = fmaf(iv.x, w0, fmaf(iv.y, w1, fmaf(iv.z, w2, fmaf(iv.w, w3, acc[r]))));
        }
    }
    int b = rb >> 8;
    int t0 = rb & 255;
#pragma unroll
    for (int r = 0; r < 16; r++)
        gin[(size_t)(((d * 8 + b) * 256) + (t0 + r)) * 512 + j] = __float2half(acc[r]);
}

// ---- LSTM recurrence v3: one block per (dir, batch) ------------------------
// thread = (column J = w*16 + (l>>2), k-chunk kc = l&3). Quad lanes share J,
// split K 4-way, reduce via shfl_xor; each quad holds all 4 gates (permuted
// gin slots J*4+g) -> in-lane c/h update. One raw lgkm-only barrier per step.
__global__ __launch_bounds__(512)
void k_lstm(const __half* __restrict__ gin, const void* __restrict__ whh,
            long long woff, __half* __restrict__ hcat,
            const u32* __restrict__ xraw) {
    __shared__ __align__(16) __half h_lds[2][128];
    int f32 = detect_f32(xraw);
    int d = blockIdx.x >> 3;
    int b = blockIdx.x & 7;
    int tid = threadIdx.x;
    int w = tid >> 6, l = tid & 63;
    int J = w * 16 + (l >> 2);
    int kc = l & 3;

    // weights: orig rows g*128+J (g=0..3 : i,f,g,o), k in [kc*32, kc*32+32)
    h2_t wreg[4][16];
#pragma unroll
    for (int g = 0; g < 4; g++) {
        long long rbase = woff + (long long)(d * 512 + g * 128 + J) * 128 + kc * 32;
        if (f32) {
            const float* p = (const float*)whh + rbase;
#pragma unroll
            for (int q = 0; q < 16; q++)
                wreg[g][q] = h2_t{(_Float16)p[q * 2], (_Float16)p[q * 2 + 1]};
        } else {
            const u32* p = (const u32*)((const u16*)whh + rbase);
#pragma unroll
            for (int q = 0; q < 16; q++) {
                u32 u = p[q];
                wreg[g][q] = h2_t{(_Float16)__uint_as_float(u << 16),
                                  (_Float16)__uint_as_float(u & 0xffff0000u)};
            }
        }
    }

    if (tid < 128) h_lds[0][tid] = __float2half(0.f);
    float c = 0.f;
    float hist[8];
    const __half* gB = gin + (size_t)((d * 8 + b) * 256) * 512 + J * 4;
    __syncthreads();

    // gin prefetch pipeline, depth 2 (survives raw barriers - no vmcnt drain)
    uint2 ga, gb_;
    {
        int tt0 = d ? 255 : 0, tt1 = d ? 254 : 1;
        ga  = *(const uint2*)(gB + (size_t)tt0 * 512);
        gb_ = *(const uint2*)(gB + (size_t)tt1 * 512);
    }

    int cur = 0;
    for (int t8 = 0; t8 < 32; t8++) {
#pragma unroll
        for (int s = 0; s < 8; s++) {
            int t = t8 * 8 + s;
            // GEMV partial over k-chunk kc (h fp16 in LDS, 16-lane-shared reads)
            float a0 = 0.f, a1 = 0.f, a2 = 0.f, a3 = 0.f;
            const uint4* hp = (const uint4*)(&h_lds[cur][kc * 32]);
#pragma unroll
            for (int i = 0; i < 4; i++) {
                uint4 u = hp[i];
                h2_t hx0 = as_h2(u.x), hx1 = as_h2(u.y), hx2 = as_h2(u.z), hx3 = as_h2(u.w);
                a0 = __builtin_amdgcn_fdot2(hx0, wreg[0][i * 4 + 0], a0, false);
                a1 = __builtin_amdgcn_fdot2(hx0, wreg[1][i * 4 + 0], a1, false);
                a2 = __builtin_amdgcn_fdot2(hx0, wreg[2][i * 4 + 0], a2, false);
                a3 = __builtin_amdgcn_fdot2(hx0, wreg[3][i * 4 + 0], a3, false);
                a0 = __builtin_amdgcn_fdot2(hx1, wreg[0][i * 4 + 1], a0, false);
                a1 = __builtin_amdgcn_fdot2(hx1, wreg[1][i * 4 + 1], a1, false);
                a2 = __builtin_amdgcn_fdot2(hx1, wreg[2][i * 4 + 1], a2, false);
                a3 = __builtin_amdgcn_fdot2(hx1, wreg[3][i * 4 + 1], a3, false);
                a0 = __builtin_amdgcn_fdot2(hx2, wreg[0][i * 4 + 2], a0, false);
                a1 = __builtin_amdgcn_fdot2(hx2, wreg[1][i * 4 + 2], a1, false);
                a2 = __builtin_amdgcn_fdot2(hx2, wreg[2][i * 4 + 2], a2, false);
                a3 = __builtin_amdgcn_fdot2(hx2, wreg[3][i * 4 + 2], a3, false);
                a0 = __builtin_amdgcn_fdot2(hx3, wreg[0][i * 4 + 3], a0, false);
                a1 = __builtin_amdgcn_fdot2(hx3, wreg[1][i * 4 + 3], a1, false);
                a2 = __builtin_amdgcn_fdot2(hx3, wreg[2][i * 4 + 3], a2, false);
                a3 = __builtin_amdgcn_fdot2(hx3, wreg[3][i * 4 + 3], a3, false);
            }
            // quad reduce (lanes J*4 .. J*4+3)
            a0 += __shfl_xor(a0, 1); a0 += __shfl_xor(a0, 2);
            a1 += __shfl_xor(a1, 1); a1 += __shfl_xor(a1, 2);
            a2 += __shfl_xor(a2, 1); a2 += __shfl_xor(a2, 2);
            a3 += __shfl_xor(a3, 1); a3 += __shfl_xor(a3, 2);
            h2_t g01 = as_h2(ga.x), g23 = as_h2(ga.y);
            float iv = sigm(a0 + (float)g01.x);
            float fv = sigm(a1 + (float)g01.y);
            float gg = tanh_f(a2 + (float)g23.x);
            float ov = sigm(a3 + (float)g23.y);
            c = fv * c + iv * gg;
            float hv = ov * tanh_f(c);
            hist[s] = hv;
            if (kc == 0) h_lds[cur ^ 1][J] = __float2half(hv);
            // rotate gin pipeline; issue load for t+2
            ga = gb_;
            int tn = (t + 2 < 256) ? (t + 2) : 255;
            int ttn = d ? (255 - tn) : tn;
            gb_ = *(const uint2*)(gB + (size_t)ttn * 512);
            bar_lds();
            cur ^= 1;
        }
        // batched h-history stores (fire-and-forget; never force-drained)
        if (kc == 0) {
            int tb_ = t8 * 8;
#pragma unroll
            for (int s = 0; s < 8; s++) {
                int tt = d ? (255 - (tb_ + s)) : (tb_ + s);
                hcat[(size_t)(b * 256 + tt) * 256 + d * 128 + J] = __float2half(hist[s]);
            }
        }
    }
}

// ---- final LayerNorm(256): M2 -> M1 (lnout fp16) + output 2 ----------------
__global__ void k_ln_out(const __half* __restrict__ in, const void* __restrict__ g,
                         const void* __restrict__ bb, __half* __restrict__ lnout,
                         void* out, const u32* __restrict__ xraw) {
    __shared__ float red1[4], red2[4];
    int f32 = detect_f32(xraw);
    int row = blockIdx.x;
    int o = threadIdx.x;
    float v = __half2float(in[row * 256 + o]);
    float s1 = v, s2 = v * v;
    for (int off = 32; off >= 1; off >>= 1) {
        s1 += __shfl_xor(s1, off, 64);
        s2 += __shfl_xor(s2, off, 64);
    }
    if ((o & 63) == 0) { red1[o >> 6] = s1; red2[o >> 6] = s2; }
    __syncthreads();
    float S1 = red1[0] + red1[1] + red1[2] + red1[3];
    float S2 = red2[0] + red2[1] + red2[2] + red2[3];
    float m = S1 * (1.0f / 256.0f);
    float var = S2 * (1.0f / 256.0f) - m * m;
    float rstd = rsqrtf(var + 1e-5f);
    float r = (v - m) * rstd * ldin(g, o, f32) + ldin(bb, o, f32);
    lnout[row * 256 + o] = __float2half(r);
    store_out(out, 526336LL + (long long)row * 256 + o, r, f32);
}

// ---- agg[b][j] = mean_t lnout[b][t][j] -> output 0 -------------------------
__global__ void k_agg(const __half* __restrict__ lnout, void* out,
                      const u32* __restrict__ xraw) {
    int f32 = detect_f32(xraw);
    int b = blockIdx.x, j = threadIdx.x;
    float s = 0.f;
    for (int t = 0; t < 256; t++) s += __half2float(lnout[(size_t)(b * 256 + t) * 256 + j]);
    store_out(out, (long long)b * 256 + j, s * (1.0f / 256.0f), f32);
}

extern "C" void kernel_launch(void* const* d_in, const int* in_sizes, int n_in,
                              void* d_out, int out_size, void* d_ws, size_t ws_size,
                              hipStream_t stream) {
    char* wsb = (char*)d_ws;
    float*  Sp   = (float*)(wsb + WB_S);
    float*  tbp  = (float*)(wsb + WB_TBP);
    float*  Wc   = (float*)(wsb + WB_WC);
    __half* WT   = (__half*)(wsb + WB_WT);
    __half* M1   = (__half*)(wsb + WB_M1);
    __half* M2   = (__half*)(wsb + WB_M2);
    __half* GIN  = (__half*)(wsb + WB_GIN);

    const u32* xraw = (const u32*)d_in[0];
    const void* x   = d_in[0];
    const void* chw = d_in[5];
    const void* chb = d_in[6];
    const void* lcg = d_in[7];
    const void* lcb = d_in[8];
    const void* wih = d_in[9];
    const void* whh = d_in[10];
    const void* bih = d_in[11];
    const void* bhh = d_in[12];
    const void* log_ = d_in[13];
    const void* lob  = d_in[14];

    k_prep<<<928, 256, 0, stream>>>(xraw, chw, wih, d_out, Wc, Sp, WT);
    k_tb1<<<64, 256, 0, stream>>>(Sp, chw, tbp, xraw);
    k_cheb_ln<<<2048, 256, 0, stream>>>(x, Wc, tbp, chb, lcg, lcb, M1, xraw);
    // layer 0
    k_gin<<<256, 512, 0, stream>>>(M1, WT, bih, bhh, GIN, 0, xraw);
    k_lstm<<<16, 512, 0, stream>>>(GIN, whh, 0LL, M2, xraw);
    // layer 1
    k_gin<<<256, 512, 0, stream>>>(M2, WT, bih, bhh, GIN, 1, xraw);
    k_lstm<<<16, 512, 0, stream>>>(GIN, whh, 131072LL, M2, xraw);
    k_ln_out<<<2048, 256, 0, stream>>>(M2, log_, lob, M1, d_out, xraw);
    k_agg<<<8, 256, 0, stream>>>(M1, d_out, xraw);
}

// Round 8
// 542.410 us; speedup vs baseline: 1.1116x; 1.1116x over previous
//
#include <hip/hip_runtime.h>
#include <hip/hip_bf16.h>
#include <hip/hip_fp16.h>

// B=8, T(N)=256, F=256, K=2, H=128, gates=512, 2H=256.
//
// Exact math simplifications (data-independent):
//  - LayerNorm over size-1 dim => TG = 1/256 exactly.
//  - A_hat rowsum == 2.0 exactly => cheb out = x@(W0+0.5*W1) + (colsum/512)@W1
//    + cheb_b -> LayerNorm(256).
//  - BiLSTM: 16 independent recurrences per layer (2 dir x 8 batch).
//
// R7->R8 (k_lstm v4): R7 regressed because (a) gin prefetch depth was
// effectively 1 step < HBM latency -> ~500cyc stall/step; (b) __shfl_xor
// lowers to ds_swizzle (LDS pipe) -> serial LDS latency back on the path;
// (c) every lane computed all 5 activations (5 exp+5 rcp, quarter-rate).
// Now: 8-step-deep gin double-buffer prefetch (survives lgkm-only barrier),
// DPP quad reduce/broadcast (VALU-rate, no LDS), single activation per lane
// via tanh(x)=2*sigm(2x)-1 (uniform, no divergence).

typedef unsigned short u16;
typedef unsigned int u32;
typedef _Float16 h2_t __attribute__((ext_vector_type(2)));

__device__ __forceinline__ float bf2f(u16 v) { return __uint_as_float(((u32)v) << 16); }
__device__ __forceinline__ u16 f2bf(float f) {
    u32 u = __float_as_uint(f);
    u32 r = (u + 0x7fffu + ((u >> 16) & 1u)) >> 16;
    return (u16)r;
}
__device__ __forceinline__ float sigm(float x) { return 1.0f / (1.0f + __expf(-x)); }
__device__ __forceinline__ float tanh_f(float x) { return 1.0f - 2.0f / (__expf(2.0f * x) + 1.0f); }
__device__ __forceinline__ float ldin(const void* p, long long i, int f32) {
    return f32 ? ((const float*)p)[i] : bf2f(((const u16*)p)[i]);
}
__device__ __forceinline__ void store_out(void* out, long long idx, float v, int f32) {
    if (f32) ((float*)out)[idx] = v;
    else ((u16*)out)[idx] = f2bf(v);
}
__device__ __forceinline__ h2_t as_h2(u32 w) { return __builtin_bit_cast(h2_t, w); }

// per-wave dtype detect: low u16 of fp32 words has random high mantissa bits;
// real bf16 data never has |x| >= 2^17.
__device__ __forceinline__ int detect_f32(const u32* __restrict__ xraw) {
    u32 w = xraw[threadIdx.x & 255];
    int e = (w >> 7) & 0xFF;
    unsigned long long m = __ballot(e >= 0x90);
    return __popcll(m) > 8;
}

// workgroup barrier draining ONLY lgkmcnt (LDS) - no vmcnt(0) drain.
__device__ __forceinline__ void bar_lds() {
    asm volatile("s_waitcnt lgkmcnt(0)\n\ts_barrier" ::: "memory");
}

// DPP quad ops (full-rate VALU, no LDS pipe)
__device__ __forceinline__ float dpp_xor1(float v) {
    return __int_as_float(__builtin_amdgcn_mov_dpp(__float_as_int(v), 0xB1, 0xF, 0xF, true));
}
__device__ __forceinline__ float dpp_xor2(float v) {
    return __int_as_float(__builtin_amdgcn_mov_dpp(__float_as_int(v), 0x4E, 0xF, 0xF, true));
}
template <int L>
__device__ __forceinline__ float dpp_bcast(float v) {
    return __int_as_float(__builtin_amdgcn_mov_dpp(__float_as_int(v), L * 0x55, 0xF, 0xF, true));
}

// ---- ws layout (BYTE offsets), total ~7.35 MB ------------------------------
#define WB_S    64        // fp32 [8192]   colsum partials (32 x 256)
#define WB_TBP  41024     // fp32 [16384]  tb partials (64 x 256)
#define WB_WC   106560    // fp32 [65536]
#define WB_WT   368704    // fp16 [524288] WihT (j-dim PERMUTED: slot J*4+g)
#define WB_M1   1417280   // fp16 [524288] hbuf0 (cheb out), later lnout
#define WB_M2   2465856   // fp16 [524288] hcat0, later hcat1
#define WB_GIN  3514432   // fp16 [2097152] gate inputs (permuted j), one layer

// ---- fused prep: wc | fill_tg | colsum | wih_t(permuted) -------------------
__global__ __launch_bounds__(256) void k_prep(const u32* __restrict__ xraw,
                                              const void* __restrict__ chw,
                                              const void* __restrict__ wih,
                                              void* out, float* __restrict__ Wc,
                                              float* __restrict__ Sp,
                                              __half* __restrict__ WT) {
    __shared__ __half tile[64][65];
    int f32 = detect_f32(xraw);
    int bid = blockIdx.x;
    int tid = threadIdx.x;
    if (bid < 256) { // Wc = W0 + 0.5*W1
        int i = bid * 256 + tid;
        Wc[i] = ldin(chw, i, f32) + 0.5f * ldin(chw, 65536 + i, f32);
    } else if (bid < 768) { // TG fill = 1/256
        long long i = (long long)(bid - 256) * 256 + tid;
        if (f32) {
            float4 v{0.00390625f, 0.00390625f, 0.00390625f, 0.00390625f};
            ((float4*)((float*)out + 2048))[i] = v;
        } else {
            uint2 v{0x3B803B80u, 0x3B803B80u};
            ((uint2*)((u16*)out + 2048))[i] = v;
        }
    } else if (bid < 800) { // colsum partials over 64 rows
        int blk = bid - 768;
        int b = blk >> 2, ch = blk & 3;
        float s = 0.f;
        int n0 = ch * 64;
        for (int n = n0; n < n0 + 64; n++)
            s += ldin(xraw, ((long long)(b * 256 + n)) * 256 + tid, f32);
        Sp[blk * 256 + tid] = s;
    } else { // wih transpose -> WT[ld][f][perm(j)], perm(j) = (j&127)*4 + (j>>7)
        int q = bid - 800;
        int ld = q >> 5;
        int jt = ((q >> 2) & 7) * 64;
        int ft = (q & 3) * 64;
        int lane = tid & 63;
        int wv = tid >> 6;
#pragma unroll
        for (int r = wv; r < 64; r += 4)
            tile[r][lane] = __float2half(ldin(wih, ((long long)(ld * 512 + jt + r)) * 256 + ft + lane, f32));
        __syncthreads();
#pragma unroll
        for (int r = wv; r < 64; r += 4) {
            int j = jt + lane;
            int pj = ((j & 127) << 2) | (j >> 7);
            WT[((long long)ld * 256 + ft + r) * 512 + pj] = tile[lane][r];
        }
    }
}

// ---- tb partials: tbp[b*8+fc][o] over f in [fc*32, fc*32+32) ---------------
__global__ void k_tb1(const float* __restrict__ Sp, const void* __restrict__ chw,
                      float* __restrict__ tbp, const u32* __restrict__ xraw) {
    int f32 = detect_f32(xraw);
    int blk = blockIdx.x;
    int b = blk >> 3, fc = blk & 7;
    int o = threadIdx.x;
    float acc = 0.f;
    const float cs = 1.0f / 512.0f;
    int f0 = fc * 32;
    for (int f = f0; f < f0 + 32; f++) {
        float s = Sp[(b * 4 + 0) * 256 + f] + Sp[(b * 4 + 1) * 256 + f] +
                  Sp[(b * 4 + 2) * 256 + f] + Sp[(b * 4 + 3) * 256 + f];
        acc = fmaf(s * cs, ldin(chw, 65536 + f * 256 + o, f32), acc);
    }
    tbp[blk * 256 + o] = acc;
}

// ---- cheb row GEMM + tb merge + LayerNorm(256) -> M1 fp16 ------------------
__global__ void k_cheb_ln(const void* __restrict__ x, const float* __restrict__ Wc,
                          const float* __restrict__ tbp, const void* __restrict__ chb,
                          const void* __restrict__ g, const void* __restrict__ bb,
                          __half* __restrict__ out, const u32* __restrict__ xraw) {
    __shared__ float xr[256];
    __shared__ float red1[4], red2[4];
    int f32 = detect_f32(xraw);
    int row = blockIdx.x;
    int b = row >> 8;
    int o = threadIdx.x;
    xr[o] = ldin(x, row * 256 + o, f32);
    __syncthreads();
    float acc = ldin(chb, o, f32);
#pragma unroll
    for (int fc = 0; fc < 8; fc++) acc += tbp[(b * 8 + fc) * 256 + o];
    const float4* x4 = (const float4*)xr;
#pragma unroll 8
    for (int q = 0; q < 64; q++) {
        float4 xv = x4[q];
        int f = q * 4;
        acc = fmaf(xv.x, Wc[f * 256 + o], acc);
        acc = fmaf(xv.y, Wc[(f + 1) * 256 + o], acc);
        acc = fmaf(xv.z, Wc[(f + 2) * 256 + o], acc);
        acc = fmaf(xv.w, Wc[(f + 3) * 256 + o], acc);
    }
    float s1 = acc, s2 = acc * acc;
    for (int off = 32; off >= 1; off >>= 1) {
        s1 += __shfl_xor(s1, off, 64);
        s2 += __shfl_xor(s2, off, 64);
    }
    if ((o & 63) == 0) { red1[o >> 6] = s1; red2[o >> 6] = s2; }
    __syncthreads();
    float S1 = red1[0] + red1[1] + red1[2] + red1[3];
    float S2 = red2[0] + red2[1] + red2[2] + red2[3];
    float m = S1 * (1.0f / 256.0f);
    float var = S2 * (1.0f / 256.0f) - m * m;
    float rstd = rsqrtf(var + 1e-5f);
    out[row * 256 + o] = __float2half((acc - m) * rstd * ldin(g, o, f32) + ldin(bb, o, f32));
}

// ---- gin[d][b][t][jr] = in[b][t] @ WT(perm) + bias(orig) -------------------
__global__ __launch_bounds__(512) void k_gin(const __half* __restrict__ in,
                                             const __half* __restrict__ WT,
                                             const void* __restrict__ bih,
                                             const void* __restrict__ bhh,
                                             __half* __restrict__ gin, int l,
                                             const u32* __restrict__ xraw) {
    __shared__ float inl[16 * 256];
    int f32 = detect_f32(xraw);
    int d = blockIdx.x >> 7;
    int rb = (blockIdx.x & 127) * 16;
    int j = threadIdx.x; // PERMUTED slot: orig row = (j&3)*128 + (j>>2)
    const __half2* src = (const __half2*)(in + (size_t)rb * 256);
    float2* dst = (float2*)inl;
#pragma unroll
    for (int q = 0; q < 4; q++)
        dst[j + q * 512] = __half22float2(src[j + q * 512]);
    __syncthreads();
    int ld = l * 2 + d;
    int oj = ((j & 3) << 7) | (j >> 2);
    float bias = ldin(bih, ld * 512 + oj, f32) + ldin(bhh, ld * 512 + oj, f32);
    float acc[16];
#pragma unroll
    for (int r = 0; r < 16; r++) acc[r] = bias;
    const __half* W = WT + (size_t)ld * 131072;
    for (int fq = 0; fq < 64; fq++) {
        int f = fq * 4;
        float w0 = __half2float(W[(f + 0) * 512 + j]);
        float w1 = __half2float(W[(f + 1) * 512 + j]);
        float w2 = __half2float(W[(f + 2) * 512 + j]);
        float w3 = __half2float(W[(f + 3) * 512 + j]);
#pragma unroll
        for (int r = 0; r < 16; r++) {
            const float4 iv = ((const float4*)(inl + r * 256))[fq];
            acc[r] = fmaf(iv.x, w0, fmaf(iv.y, w1, fmaf(iv.z, w2, fmaf(iv.w, w3, acc[r]))));
        }
    }
    int b = rb >> 8;
    int t0 = rb & 255;
#pragma unroll
    for (int r = 0; r < 16; r++)
        gin[(size_t)(((d * 8 + b) * 256) + (t0 + r)) * 512 + j] = __float2half(acc[r]);
}

// ---- LSTM recurrence v4: one block per (dir, batch) ------------------------
// thread = (column J, k-chunk kc = lane&3). Quad shares J, splits K 4-way.
// DPP quad reduce + single activation per lane + DPP gate broadcast.
// gin prefetched 8 steps deep (block double-buffer). One lgkm barrier/step.
__global__ __launch_bounds__(512)
void k_lstm(const __half* __restrict__ gin, const void* __restrict__ whh,
            long long woff, __half* __restrict__ hcat,
            const u32* __restrict__ xraw) {
    __shared__ __align__(16) __half h_lds[2][128];
    int f32 = detect_f32(xraw);
    int d = blockIdx.x >> 3;
    int b = blockIdx.x & 7;
    int tid = threadIdx.x;
    int w = tid >> 6, l = tid & 63;
    int J = w * 16 + (l >> 2);
    int kc = l & 3;

    // weights: orig rows g*128+J (g=0..3 : i,f,g,o), k in [kc*32, kc*32+32)
    h2_t wreg[4][16];
#pragma unroll
    for (int g = 0; g < 4; g++) {
        long long rbase = woff + (long long)(d * 512 + g * 128 + J) * 128 + kc * 32;
        if (f32) {
            const float* p = (const float*)whh + rbase;
#pragma unroll
            for (int q = 0; q < 16; q++)
                wreg[g][q] = h2_t{(_Float16)p[q * 2], (_Float16)p[q * 2 + 1]};
        } else {
            const u32* p = (const u32*)((const u16*)whh + rbase);
#pragma unroll
            for (int q = 0; q < 16; q++) {
                u32 u = p[q];
                wreg[g][q] = h2_t{(_Float16)__uint_as_float(u << 16),
                                  (_Float16)__uint_as_float(u & 0xffff0000u)};
            }
        }
    }

    if (tid < 128) h_lds[0][tid] = __float2half(0.f);
    float c = 0.f;
    float hist[8];
    const __half* gB = gin + (size_t)((d * 8 + b) * 256) * 512 + J * 4;
    __syncthreads();

    // 8-step-deep gin prefetch: double-buffered register blocks
    uint2 gv8[8], gn8[8];
#pragma unroll
    for (int s = 0; s < 8; s++) {
        int tt = d ? (255 - s) : s;
        gv8[s] = *(const uint2*)(gB + (size_t)tt * 512);
    }

    int cur = 0;
    for (int t8 = 0; t8 < 32; t8++) {
        if (t8 < 31) { // issue next block's loads; consumed at block end
#pragma unroll
            for (int s = 0; s < 8; s++) {
                int t = (t8 + 1) * 8 + s;
                int tt = d ? (255 - t) : t;
                gn8[s] = *(const uint2*)(gB + (size_t)tt * 512);
            }
        }
#pragma unroll
        for (int s = 0; s < 8; s++) {
            // GEMV partial over k-chunk kc (h fp16 in LDS, 16-lane-shared)
            float a0 = 0.f, a1 = 0.f, a2 = 0.f, a3 = 0.f;
            const uint4* hp = (const uint4*)(&h_lds[cur][kc * 32]);
#pragma unroll
            for (int i = 0; i < 4; i++) {
                uint4 u = hp[i];
                h2_t hx0 = as_h2(u.x), hx1 = as_h2(u.y), hx2 = as_h2(u.z), hx3 = as_h2(u.w);
                a0 = __builtin_amdgcn_fdot2(hx0, wreg[0][i * 4 + 0], a0, false);
                a1 = __builtin_amdgcn_fdot2(hx0, wreg[1][i * 4 + 0], a1, false);
                a2 = __builtin_amdgcn_fdot2(hx0, wreg[2][i * 4 + 0], a2, false);
                a3 = __builtin_amdgcn_fdot2(hx0, wreg[3][i * 4 + 0], a3, false);
                a0 = __builtin_amdgcn_fdot2(hx1, wreg[0][i * 4 + 1], a0, false);
                a1 = __builtin_amdgcn_fdot2(hx1, wreg[1][i * 4 + 1], a1, false);
                a2 = __builtin_amdgcn_fdot2(hx1, wreg[2][i * 4 + 1], a2, false);
                a3 = __builtin_amdgcn_fdot2(hx1, wreg[3][i * 4 + 1], a3, false);
                a0 = __builtin_amdgcn_fdot2(hx2, wreg[0][i * 4 + 2], a0, false);
                a1 = __builtin_amdgcn_fdot2(hx2, wreg[1][i * 4 + 2], a1, false);
                a2 = __builtin_amdgcn_fdot2(hx2, wreg[2][i * 4 + 2], a2, false);
                a3 = __builtin_amdgcn_fdot2(hx2, wreg[3][i * 4 + 2], a3, false);
                a0 = __builtin_amdgcn_fdot2(hx3, wreg[0][i * 4 + 3], a0, false);
                a1 = __builtin_amdgcn_fdot2(hx3, wreg[1][i * 4 + 3], a1, false);
                a2 = __builtin_amdgcn_fdot2(hx3, wreg[2][i * 4 + 3], a2, false);
                a3 = __builtin_amdgcn_fdot2(hx3, wreg[3][i * 4 + 3], a3, false);
            }
            // DPP quad reduce (VALU-rate)
            a0 += dpp_xor1(a0); a0 += dpp_xor2(a0);
            a1 += dpp_xor1(a1); a1 += dpp_xor2(a1);
            a2 += dpp_xor1(a2); a2 += dpp_xor2(a2);
            a3 += dpp_xor1(a3); a3 += dpp_xor2(a3);
            // per-lane gate kc pre-activation (uniform: tanh via 2*sigm(2x)-1)
            h2_t g01 = as_h2(gv8[s].x), g23 = as_h2(gv8[s].y);
            float pre = (kc == 0) ? a0 + (float)g01.x
                      : (kc == 1) ? a1 + (float)g01.y
                      : (kc == 2) ? a2 + (float)g23.x
                                  : a3 + (float)g23.y;
            float px = (kc == 2) ? 2.0f * pre : pre;
            float sg = 1.0f / (1.0f + __expf(-px));
            float act = (kc == 2) ? 2.0f * sg - 1.0f : sg;
            // broadcast all 4 gates across the quad
            float iv = dpp_bcast<0>(act);
            float fv = dpp_bcast<1>(act);
            float gv = dpp_bcast<2>(act);
            float ov = dpp_bcast<3>(act);
            c = fv * c + iv * gv;
            float e2 = __expf(-2.0f * c);
            float tc = 2.0f / (1.0f + e2) - 1.0f; // tanh(c)
            float hv = ov * tc;
            hist[s] = hv;
            if (kc == 0) h_lds[cur ^ 1][J] = __float2half(hv);
            bar_lds();
            cur ^= 1;
        }
        // rotate prefetch buffer (waits vmcnt for gn8 loads: 8 steps of slack)
#pragma unroll
        for (int s = 0; s < 8; s++) gv8[s] = gn8[s];
        // batched h-history stores (fire-and-forget)
        if (kc == 0) {
            int tb_ = t8 * 8;
#pragma unroll
            for (int s = 0; s < 8; s++) {
                int tt = d ? (255 - (tb_ + s)) : (tb_ + s);
                hcat[(size_t)(b * 256 + tt) * 256 + d * 128 + J] = __float2half(hist[s]);
            }
        }
    }
}

// ---- final LayerNorm(256): M2 -> M1 (lnout fp16) + output 2 ----------------
__global__ void k_ln_out(const __half* __restrict__ in, const void* __restrict__ g,
                         const void* __restrict__ bb, __half* __restrict__ lnout,
                         void* out, const u32* __restrict__ xraw) {
    __shared__ float red1[4], red2[4];
    int f32 = detect_f32(xraw);
    int row = blockIdx.x;
    int o = threadIdx.x;
    float v = __half2float(in[row * 256 + o]);
    float s1 = v, s2 = v * v;
    for (int off = 32; off >= 1; off >>= 1) {
        s1 += __shfl_xor(s1, off, 64);
        s2 += __shfl_xor(s2, off, 64);
    }
    if ((o & 63) == 0) { red1[o >> 6] = s1; red2[o >> 6] = s2; }
    __syncthreads();
    float S1 = red1[0] + red1[1] + red1[2] + red1[3];
    float S2 = red2[0] + red2[1] + red2[2] + red2[3];
    float m = S1 * (1.0f / 256.0f);
    float var = S2 * (1.0f / 256.0f) - m * m;
    float rstd = rsqrtf(var + 1e-5f);
    float r = (v - m) * rstd * ldin(g, o, f32) + ldin(bb, o, f32);
    lnout[row * 256 + o] = __float2half(r);
    store_out(out, 526336LL + (long long)row * 256 + o, r, f32);
}

// ---- agg[b][j] = mean_t lnout[b][t][j] -> output 0 -------------------------
__global__ void k_agg(const __half* __restrict__ lnout, void* out,
                      const u32* __restrict__ xraw) {
    int f32 = detect_f32(xraw);
    int b = blockIdx.x, j = threadIdx.x;
    float s = 0.f;
    for (int t = 0; t < 256; t++) s += __half2float(lnout[(size_t)(b * 256 + t) * 256 + j]);
    store_out(out, (long long)b * 256 + j, s * (1.0f / 256.0f), f32);
}

extern "C" void kernel_launch(void* const* d_in, const int* in_sizes, int n_in,
                              void* d_out, int out_size, void* d_ws, size_t ws_size,
                              hipStream_t stream) {
    char* wsb = (char*)d_ws;
    float*  Sp   = (float*)(wsb + WB_S);
    float*  tbp  = (float*)(wsb + WB_TBP);
    float*  Wc   = (float*)(wsb + WB_WC);
    __half* WT   = (__half*)(wsb + WB_WT);
    __half* M1   = (__half*)(wsb + WB_M1);
    __half* M2   = (__half*)(wsb + WB_M2);
    __half* GIN  = (__half*)(wsb + WB_GIN);

    const u32* xraw = (const u32*)d_in[0];
    const void* x   = d_in[0];
    const void* chw = d_in[5];
    const void* chb = d_in[6];
    const void* lcg = d_in[7];
    const void* lcb = d_in[8];
    const void* wih = d_in[9];
    const void* whh = d_in[10];
    const void* bih = d_in[11];
    const void* bhh = d_in[12];
    const void* log_ = d_in[13];
    const void* lob  = d_in[14];

    k_prep<<<928, 256, 0, stream>>>(xraw, chw, wih, d_out, Wc, Sp, WT);
    k_tb1<<<64, 256, 0, stream>>>(Sp, chw, tbp, xraw);
    k_cheb_ln<<<2048, 256, 0, stream>>>(x, Wc, tbp, chb, lcg, lcb, M1, xraw);
    // layer 0
    k_gin<<<256, 512, 0, stream>>>(M1, WT, bih, bhh, GIN, 0, xraw);
    k_lstm<<<16, 512, 0, stream>>>(GIN, whh, 0LL, M2, xraw);
    // layer 1
    k_gin<<<256, 512, 0, stream>>>(M2, WT, bih, bhh, GIN, 1, xraw);
    k_lstm<<<16, 512, 0, stream>>>(GIN, whh, 131072LL, M2, xraw);
    k_ln_out<<<2048, 256, 0, stream>>>(M2, log_, lob, M1, d_out, xraw);
    k_agg<<<8, 256, 0, stream>>>(M1, d_out, xraw);
}